// Round 1
// baseline (484.279 us; speedup 1.0000x reference)
//
#include <hip/hip_runtime.h>
#include <hip/hip_fp16.h>

#define HASH_PRIME 5099
#define NE 64
#define ND 512
#define NF 1792
#define NS 32768
#define CAP 512

typedef unsigned short u16;
typedef __attribute__((ext_vector_type(8))) short bf16x8;
typedef __attribute__((ext_vector_type(4))) float f32x4;

__device__ __forceinline__ u16 f2bf(float f) {
  union { float f; unsigned u; } v; v.f = f;
  return (u16)((v.u + 0x7FFFu + ((v.u >> 16) & 1u)) >> 16);
}
__device__ __forceinline__ unsigned pk2(float a, float b) {
  return (unsigned)f2bf(a) | ((unsigned)f2bf(b) << 16);
}
__device__ __forceinline__ unsigned pkh2(float a, float b) {
  __half2 h = __floats2half2_rn(a, b);
  return __builtin_bit_cast(unsigned, h);
}
__device__ __forceinline__ float uph(unsigned w, int hi) {
  __half2 h = __builtin_bit_cast(__half2, w);
  return hi ? __high2float(h) : __low2float(h);
}

// ---------------- routing ----------------
__global__ __launch_bounds__(512) void route1(const int* __restrict__ tok,
                                              int* __restrict__ rank_local,
                                              int* __restrict__ hist) {
  __shared__ int se[512];
  __shared__ int h[NE];
  int b = blockIdx.x, t = threadIdx.x;
  int s = b * 512 + t;
  int e = (tok[s] % HASH_PRIME) % NE;
  se[t] = e;
  if (t < NE) h[t] = 0;
  __syncthreads();
  int cnt = 0;
  for (int j = 0; j < t; ++j) cnt += (se[j] == e);
  rank_local[s] = cnt;
  atomicAdd(&h[e], 1);
  __syncthreads();
  if (t < NE) hist[b * NE + t] = h[t];
}

__global__ __launch_bounds__(512) void route2(const int* __restrict__ tok,
                                              const int* __restrict__ rank_local,
                                              const int* __restrict__ hist,
                                              int* __restrict__ slot_src) {
  __shared__ int off[NE];
  int b = blockIdx.x, t = threadIdx.x;
  if (t < NE) {
    int o = 0;
    for (int bb = 0; bb < b; ++bb) o += hist[bb * NE + t];
    off[t] = o;
  }
  __syncthreads();
  int s = b * 512 + t;
  int e = (tok[s] % HASH_PRIME) % NE;
  int pos = off[e] + rank_local[s];
  if (pos < CAP) slot_src[e * CAP + pos] = s;
}

// ---------------- GEMM machinery ----------------
// 128x128 tile, BK=32, 256 threads = 4 waves (2x2), each wave 64x64 via 4x4
// mfma_f32_16x16x32_bf16 fragments. LDS rows padded to 40 bf16 (80 B) -> <=2-way
// bank conflicts on ds_read_b128 (free per m136).

#define TILE_DECL \
  __shared__ u16 As[2][128][40]; \
  __shared__ u16 Bs[2][128][40]; \
  __shared__ int ss[128]; \
  const int t = threadIdx.x; \
  const int l = t & 63; \
  const int wr = t >> 7; \
  const int wc = (t >> 6) & 1; \
  const int lrow = l & 15; \
  const int koff = (l >> 4) * 8; \
  const int row = t >> 1; \
  const int half = t & 1;

#define COMPUTE(buf, ACC) do { \
  bf16x8 af_[4], bf_[4]; \
  _Pragma("unroll") for (int m_ = 0; m_ < 4; ++m_) \
    af_[m_] = *(const bf16x8*)&As[buf][wr * 64 + m_ * 16 + lrow][koff]; \
  _Pragma("unroll") for (int n_ = 0; n_ < 4; ++n_) \
    bf_[n_] = *(const bf16x8*)&Bs[buf][wc * 64 + n_ * 16 + lrow][koff]; \
  _Pragma("unroll") for (int m_ = 0; m_ < 4; ++m_) \
    _Pragma("unroll") for (int n_ = 0; n_ < 4; ++n_) \
      ACC[m_][n_] = __builtin_amdgcn_mfma_f32_16x16x32_bf16(af_[m_], bf_[n_], ACC[m_][n_], 0, 0, 0); \
} while (0)

#define LOAD_F32(dst, base, k0) do { \
  const float4* p_ = (const float4*)((base) + (k0)); \
  dst[0] = p_[0]; dst[1] = p_[1]; dst[2] = p_[2]; dst[3] = p_[3]; \
} while (0)

#define LOAD_X(dst, k0) do { \
  if (srow >= 0) { \
    const float4* p_ = (const float4*)(x + (size_t)srow * ND + (k0) + half * 16); \
    dst[0] = p_[0]; dst[1] = p_[1]; dst[2] = p_[2]; dst[3] = p_[3]; \
  } else { \
    float4 z_ = make_float4(0.f, 0.f, 0.f, 0.f); \
    dst[0] = z_; dst[1] = z_; dst[2] = z_; dst[3] = z_; \
  } \
} while (0)

#define WRITE_BF(arr, buf, r4) do { \
  uint4 w0_, w1_; \
  w0_.x = pk2(r4[0].x, r4[0].y); w0_.y = pk2(r4[0].z, r4[0].w); \
  w0_.z = pk2(r4[1].x, r4[1].y); w0_.w = pk2(r4[1].z, r4[1].w); \
  w1_.x = pk2(r4[2].x, r4[2].y); w1_.y = pk2(r4[2].z, r4[2].w); \
  w1_.z = pk2(r4[3].x, r4[3].y); w1_.w = pk2(r4[3].z, r4[3].w); \
  *(uint4*)&arr[buf][row][half * 16]     = w0_; \
  *(uint4*)&arr[buf][row][half * 16 + 8] = w1_; \
} while (0)

#define INIT_ACC(ACC) do { \
  _Pragma("unroll") for (int m_ = 0; m_ < 4; ++m_) \
    _Pragma("unroll") for (int n_ = 0; n_ < 4; ++n_) \
      ACC[m_][n_] = (f32x4){0.f, 0.f, 0.f, 0.f}; \
} while (0)

// ---------------- G1: H = relu(X Wk^T)^2, bf16 ----------------
__global__ __launch_bounds__(256) void g1(const float* __restrict__ x,
                                          const float* __restrict__ Wk,
                                          const int* __restrict__ slot_src,
                                          u16* __restrict__ H) {
  TILE_DECL
  const int e  = blockIdx.z;
  const int m0 = blockIdx.y * 128;  // slot rows
  const int n0 = blockIdx.x * 128;  // f cols
  if (t < 128) ss[t] = slot_src[e * CAP + m0 + t];
  __syncthreads();
  const int srow = ss[row];

  const float* bbase = Wk + ((size_t)e * NF + n0 + row) * ND + half * 16;

  f32x4 acc[4][4];
  INIT_ACC(acc);

  float4 ra[4], rb[4];
  LOAD_X(ra, 0);
  LOAD_F32(rb, bbase, 0);
  WRITE_BF(As, 0, ra);
  WRITE_BF(Bs, 0, rb);
  __syncthreads();
  #pragma unroll 2
  for (int ks = 0; ks < 16; ++ks) {
    const int cur = ks & 1;
    if (ks < 15) { LOAD_X(ra, (ks + 1) * 32); LOAD_F32(rb, bbase, (ks + 1) * 32); }
    COMPUTE(cur, acc);
    if (ks < 15) { WRITE_BF(As, cur ^ 1, ra); WRITE_BF(Bs, cur ^ 1, rb); }
    __syncthreads();
  }

  // epilogue: h = relu(z)^2 -> bf16
  #pragma unroll
  for (int m = 0; m < 4; ++m) {
    #pragma unroll
    for (int i = 0; i < 4; ++i) {
      int r = m0 + wr * 64 + m * 16 + (l >> 4) * 4 + i;
      size_t base = ((size_t)e * CAP + r) * NF + n0 + wc * 64 + lrow;
      #pragma unroll
      for (int n = 0; n < 4; ++n) {
        float v = acc[m][n][i];
        v = v > 0.f ? v * v : 0.f;
        H[base + n * 16] = f2bf(v);
      }
    }
  }
}

// ---------------- G2: out = sigmoid(X Wr^T) * (H Wv^T), scatter ----------------
__global__ __launch_bounds__(256) void g2(const float* __restrict__ x,
                                          const float* __restrict__ Wr,
                                          const float* __restrict__ Wv,
                                          const u16* __restrict__ H,
                                          const int* __restrict__ slot_src,
                                          float* __restrict__ out) {
  TILE_DECL
  const int e  = blockIdx.z;
  const int m0 = blockIdx.y * 128;  // slot rows
  const int n0 = blockIdx.x * 128;  // d cols
  if (t < 128) ss[t] = slot_src[e * CAP + m0 + t];
  __syncthreads();
  const int srow = ss[row];

  f32x4 acc[4][4];

  // ---- phase 1: zr = X Wr^T ----
  {
    const float* bbase = Wr + ((size_t)e * ND + n0 + row) * ND + half * 16;
    INIT_ACC(acc);
    float4 ra[4], rb[4];
    LOAD_X(ra, 0);
    LOAD_F32(rb, bbase, 0);
    WRITE_BF(As, 0, ra);
    WRITE_BF(Bs, 0, rb);
    __syncthreads();
    #pragma unroll 2
    for (int ks = 0; ks < 16; ++ks) {
      const int cur = ks & 1;
      if (ks < 15) { LOAD_X(ra, (ks + 1) * 32); LOAD_F32(rb, bbase, (ks + 1) * 32); }
      COMPUTE(cur, acc);
      if (ks < 15) { WRITE_BF(As, cur ^ 1, ra); WRITE_BF(Bs, cur ^ 1, rb); }
      __syncthreads();
    }
  }

  // pack r = sigmoid(zr) as fp16 pairs (rel err ~5e-4, halves register cost)
  unsigned rpk[4][4][2];
  #pragma unroll
  for (int m = 0; m < 4; ++m) {
    #pragma unroll
    for (int n = 0; n < 4; ++n) {
      float r0 = 1.f / (1.f + __expf(-acc[m][n][0]));
      float r1 = 1.f / (1.f + __expf(-acc[m][n][1]));
      float r2 = 1.f / (1.f + __expf(-acc[m][n][2]));
      float r3 = 1.f / (1.f + __expf(-acc[m][n][3]));
      rpk[m][n][0] = pkh2(r0, r1);
      rpk[m][n][1] = pkh2(r2, r3);
    }
  }

  // ---- phase 2: kv = H Wv^T ----
  {
    const u16*   abase = H  + ((size_t)e * CAP + m0 + row) * NF + half * 16;
    const float* bbase = Wv + ((size_t)e * ND + n0 + row) * NF + half * 16;
    INIT_ACC(acc);
    uint4 ua0, ua1;
    float4 rb[4];
    { const uint4* p = (const uint4*)(abase); ua0 = p[0]; ua1 = p[1]; }
    LOAD_F32(rb, bbase, 0);
    *(uint4*)&As[0][row][half * 16]     = ua0;
    *(uint4*)&As[0][row][half * 16 + 8] = ua1;
    WRITE_BF(Bs, 0, rb);
    __syncthreads();
    #pragma unroll 2
    for (int ks = 0; ks < 56; ++ks) {
      const int cur = ks & 1;
      if (ks < 55) {
        const uint4* p = (const uint4*)(abase + (ks + 1) * 32);
        ua0 = p[0]; ua1 = p[1];
        LOAD_F32(rb, bbase, (ks + 1) * 32);
      }
      COMPUTE(cur, acc);
      if (ks < 55) {
        *(uint4*)&As[cur ^ 1][row][half * 16]     = ua0;
        *(uint4*)&As[cur ^ 1][row][half * 16 + 8] = ua1;
        WRITE_BF(Bs, cur ^ 1, rb);
      }
      __syncthreads();
    }
  }

  // epilogue: out = r * kv, scatter rows to d_out (dropped tokens stay 0)
  #pragma unroll
  for (int m = 0; m < 4; ++m) {
    #pragma unroll
    for (int i = 0; i < 4; ++i) {
      int r = wr * 64 + m * 16 + (l >> 4) * 4 + i;  // tile-local slot row
      int s = ss[r];
      if (s >= 0) {
        size_t base = (size_t)s * ND + n0 + wc * 64 + lrow;
        #pragma unroll
        for (int n = 0; n < 4; ++n) {
          float kv = acc[m][n][i];
          float rr = uph(rpk[m][n][i >> 1], i & 1);
          out[base + n * 16] = rr * kv;
        }
      }
    }
  }
}

extern "C" void kernel_launch(void* const* d_in, const int* in_sizes, int n_in,
                              void* d_out, int out_size, void* d_ws, size_t ws_size,
                              hipStream_t stream) {
  const float* x  = (const float*)d_in[0];
  const int*   tok = (const int*)d_in[1];
  const float* Wk = (const float*)d_in[2];
  const float* Wr = (const float*)d_in[3];
  const float* Wv = (const float*)d_in[4];
  float* out = (float*)d_out;

  char* ws = (char*)d_ws;
  int* slot_src   = (int*)ws;                  // 64*512*4   = 131072 B
  int* rank_local = (int*)(ws + 131072);       // 32768*4    = 131072 B
  int* hist       = (int*)(ws + 262144);       // 64*64*4    = 16384 B
  u16* H          = (u16*)(ws + (1 << 20));    // 64*512*1792*2 = 117440512 B

  hipMemsetAsync(d_out, 0, (size_t)out_size * sizeof(float), stream);
  hipMemsetAsync(slot_src, 0xFF, NE * CAP * sizeof(int), stream);
  route1<<<64, 512, 0, stream>>>(tok, rank_local, hist);
  route2<<<64, 512, 0, stream>>>(tok, rank_local, hist, slot_src);
  g1<<<dim3(NF / 128, CAP / 128, NE), 256, 0, stream>>>(x, Wk, slot_src, H);
  g2<<<dim3(ND / 128, CAP / 128, NE), 256, 0, stream>>>(x, Wr, Wv, H, slot_src, out);
}

// Round 3
// 343.448 us; speedup vs baseline: 1.4101x; 1.4101x over previous
//
#include <hip/hip_runtime.h>
#include <hip/hip_fp16.h>

#define HASH_PRIME 5099
#define NE 64
#define ND 512
#define NF 1792
#define NS 32768
#define CAP 512

typedef unsigned short u16;
typedef __attribute__((ext_vector_type(8))) short bf16x8;
typedef __attribute__((ext_vector_type(4))) float f32x4;

__device__ __forceinline__ u16 f2bf(float f) {
  union { float f; unsigned u; } v; v.f = f;
  return (u16)((v.u + 0x7FFFu + ((v.u >> 16) & 1u)) >> 16);
}
__device__ __forceinline__ unsigned pkbf2(float a, float b) {
  return (unsigned)f2bf(a) | ((unsigned)f2bf(b) << 16);
}

// async global->LDS, 16B per lane. LDS dest is wave-uniform base + lane*16.
__device__ __forceinline__ void gld16(const void* g, void* l) {
  __builtin_amdgcn_global_load_lds(
      (const __attribute__((address_space(1))) unsigned int*)(uintptr_t)g,
      (__attribute__((address_space(3))) unsigned int*)(uintptr_t)l,
      16, 0, 0);
}

// ---------------- routing ----------------
__global__ __launch_bounds__(512) void route1(const int* __restrict__ tok,
                                              int* __restrict__ rank_local,
                                              int* __restrict__ hist) {
  __shared__ int se[512];
  __shared__ int h[NE];
  int b = blockIdx.x, t = threadIdx.x;
  int s = b * 512 + t;
  int e = (tok[s] % HASH_PRIME) % NE;
  se[t] = e;
  if (t < NE) h[t] = 0;
  __syncthreads();
  int cnt = 0;
  for (int j = 0; j < t; ++j) cnt += (se[j] == e);
  rank_local[s] = cnt;
  atomicAdd(&h[e], 1);
  __syncthreads();
  if (t < NE) hist[b * NE + t] = h[t];
}

__global__ __launch_bounds__(512) void route2(const int* __restrict__ tok,
                                              const int* __restrict__ rank_local,
                                              const int* __restrict__ hist,
                                              int* __restrict__ slot_src) {
  __shared__ int off[NE];
  int b = blockIdx.x, t = threadIdx.x;
  if (t < NE) {
    int o = 0;
    for (int bb = 0; bb < b; ++bb) o += hist[bb * NE + t];
    off[t] = o;
  }
  __syncthreads();
  int s = b * 512 + t;
  int e = (tok[s] % HASH_PRIME) % NE;
  int pos = off[e] + rank_local[s];
  if (pos < CAP) slot_src[e * CAP + pos] = s;
}

// ---------------- dispatch: gather X -> bf16 Xd[E,CAP,D], zero dropped ----------------
__global__ __launch_bounds__(256) void dispatchx(const float* __restrict__ x,
                                                 const int* __restrict__ slot_src,
                                                 u16* __restrict__ Xd) {
  int b = blockIdx.x;           // 8192 blocks, 4 rows each
  int t = threadIdx.x;
  int row = b * 4 + (t >> 6);   // e*CAP + c
  int col = (t & 63) * 8;
  int s = slot_src[row];
  uint4 w = make_uint4(0u, 0u, 0u, 0u);
  if (s >= 0) {
    const float4* p = (const float4*)(x + (size_t)s * ND + col);
    float4 a = p[0], c = p[1];
    w.x = pkbf2(a.x, a.y); w.y = pkbf2(a.z, a.w);
    w.z = pkbf2(c.x, c.y); w.w = pkbf2(c.z, c.w);
  }
  *(uint4*)(Xd + (size_t)row * ND + col) = w;
}

// ---------------- GEMM machinery ----------------
// 256x128 tile, BK=32, 512 threads = 8 waves (4m x 2n), each wave 64x64 via
// 4x4 mfma_f32_16x16x32_bf16. LDS rows 32 bf16 = 64 B, linear (m97 pattern:
// frag reads are 1024-B contiguous per wave -> conflict-free, no pad).
// A staged via global_load_lds (bf16 source); B (f32 weights) reg-staged + cvt_pk.

#define GDECL \
  __shared__ u16 As[2][256 * 32]; \
  __shared__ u16 Bs[2][128 * 32]; \
  const int t = threadIdx.x; \
  const int l = t & 63; \
  const int w = t >> 6; \
  const int wm = w >> 1; \
  const int wn = w & 1; \
  const int lrow = l & 15; \
  const int kb = l >> 4; \
  const int brow = t >> 2; \
  const int bseg = t & 3;

#define INIT_ACC do { \
  _Pragma("unroll") for (int m_ = 0; m_ < 4; ++m_) \
    _Pragma("unroll") for (int n_ = 0; n_ < 4; ++n_) \
      acc[m_][n_] = (f32x4){0.f, 0.f, 0.f, 0.f}; \
} while (0)

#define ISSUE_A(buf, ks, abase, astride) do { \
  const u16* g_ = (abase) + (size_t)(w * 32 + (l >> 2)) * (astride) + (ks) * 32 + (l & 3) * 8; \
  gld16(g_, (char*)&As[buf][0] + w * 2048); \
  gld16(g_ + (size_t)16 * (astride), (char*)&As[buf][0] + w * 2048 + 1024); \
} while (0)

#define LOAD_B(ks, bbase, bstride) do { \
  const float4* p_ = (const float4*)((bbase) + (size_t)brow * (bstride) + (ks) * 32 + bseg * 8); \
  fb0 = p_[0]; fb1 = p_[1]; \
} while (0)

#define WRITE_B(buf) do { \
  uint4 wv_; \
  wv_.x = pkbf2(fb0.x, fb0.y); wv_.y = pkbf2(fb0.z, fb0.w); \
  wv_.z = pkbf2(fb1.x, fb1.y); wv_.w = pkbf2(fb1.z, fb1.w); \
  *(uint4*)&Bs[buf][brow * 32 + bseg * 8] = wv_; \
} while (0)

#define COMPUTE(buf) do { \
  bf16x8 af_[4], bf_[4]; \
  _Pragma("unroll") for (int m_ = 0; m_ < 4; ++m_) \
    af_[m_] = *(const bf16x8*)&As[buf][(wm * 64 + m_ * 16 + lrow) * 32 + kb * 8]; \
  _Pragma("unroll") for (int n_ = 0; n_ < 4; ++n_) \
    bf_[n_] = *(const bf16x8*)&Bs[buf][(wn * 64 + n_ * 16 + lrow) * 32 + kb * 8]; \
  _Pragma("unroll") for (int m_ = 0; m_ < 4; ++m_) \
    _Pragma("unroll") for (int n_ = 0; n_ < 4; ++n_) \
      acc[m_][n_] = __builtin_amdgcn_mfma_f32_16x16x32_bf16(af_[m_], bf_[n_], acc[m_][n_], 0, 0, 0); \
} while (0)

#define GEMM_LOOP(NK, abase, astride, bbase, bstride) do { \
  float4 fb0, fb1; \
  ISSUE_A(0, 0, abase, astride); \
  LOAD_B(0, bbase, bstride); \
  WRITE_B(0); \
  __syncthreads(); \
  _Pragma("unroll 2") \
  for (int ks = 0; ks < (NK); ++ks) { \
    const int cur = ks & 1; \
    if (ks + 1 < (NK)) { \
      ISSUE_A(cur ^ 1, ks + 1, abase, astride); \
      LOAD_B(ks + 1, bbase, bstride); \
    } \
    COMPUTE(cur); \
    if (ks + 1 < (NK)) WRITE_B(cur ^ 1); \
    __syncthreads(); \
  } \
} while (0)

// ---------------- G1: H = relu(Xd Wk^T)^2, bf16 ----------------
__global__ __launch_bounds__(512, 4) void g1(const u16* __restrict__ Xd,
                                             const float* __restrict__ Wk,
                                             u16* __restrict__ H) {
  GDECL
  // 1792 blocks: bijective XCD swizzle, 8 experts per XCD, m innermost
  const int wg = (blockIdx.x & 7) * (1792 / 8) + (blockIdx.x >> 3);
  const int e = wg / 28, rem = wg % 28;
  const int n0 = (rem >> 1) * 128;
  const int m0 = (rem & 1) * 256;
  f32x4 acc[4][4];
  INIT_ACC;
  const u16*  abase = Xd + ((size_t)e * CAP + m0) * ND;
  const float* bbase = Wk + ((size_t)e * NF + n0) * ND;
  GEMM_LOOP(16, abase, ND, bbase, ND);

  #pragma unroll
  for (int m = 0; m < 4; ++m) {
    #pragma unroll
    for (int i = 0; i < 4; ++i) {
      int r = m0 + wm * 64 + m * 16 + (l >> 4) * 4 + i;
      size_t base = ((size_t)e * CAP + r) * NF + n0 + wn * 64 + lrow;
      #pragma unroll
      for (int n = 0; n < 4; ++n) {
        float v = acc[m][n][i];
        v = v > 0.f ? v * v : 0.f;
        H[base + n * 16] = f2bf(v);
      }
    }
  }
}

// ---------------- G2a: R = sigmoid(Xd Wr^T), fp16 ----------------
__global__ __launch_bounds__(512, 4) void g2a(const u16* __restrict__ Xd,
                                              const float* __restrict__ Wr,
                                              __half* __restrict__ R) {
  GDECL
  // 512 blocks
  const int wg = (blockIdx.x & 7) * (512 / 8) + (blockIdx.x >> 3);
  const int e = wg / 8, rem = wg % 8;
  const int n0 = (rem >> 1) * 128;
  const int m0 = (rem & 1) * 256;
  f32x4 acc[4][4];
  INIT_ACC;
  const u16*  abase = Xd + ((size_t)e * CAP + m0) * ND;
  const float* bbase = Wr + ((size_t)e * ND + n0) * ND;
  GEMM_LOOP(16, abase, ND, bbase, ND);

  #pragma unroll
  for (int m = 0; m < 4; ++m) {
    #pragma unroll
    for (int i = 0; i < 4; ++i) {
      int r = m0 + wm * 64 + m * 16 + (l >> 4) * 4 + i;
      size_t base = ((size_t)e * CAP + r) * ND + n0 + wn * 64 + lrow;
      #pragma unroll
      for (int n = 0; n < 4; ++n) {
        float s = 1.f / (1.f + __expf(-acc[m][n][i]));
        R[base + n * 16] = __float2half(s);
      }
    }
  }
}

// ---------------- G2b: out = R * (H Wv^T), scatter ----------------
__global__ __launch_bounds__(512, 4) void g2b(const u16* __restrict__ H,
                                              const float* __restrict__ Wv,
                                              const __half* __restrict__ R,
                                              const int* __restrict__ slot_src,
                                              float* __restrict__ out) {
  GDECL
  __shared__ int ss[256];
  const int wg = (blockIdx.x & 7) * (512 / 8) + (blockIdx.x >> 3);
  const int e = wg / 8, rem = wg % 8;
  const int n0 = (rem >> 1) * 128;
  const int m0 = (rem & 1) * 256;
  if (t < 256) ss[t] = slot_src[e * CAP + m0 + t];
  f32x4 acc[4][4];
  INIT_ACC;
  const u16*  abase = H  + ((size_t)e * CAP + m0) * NF;
  const float* bbase = Wv + ((size_t)e * ND + n0) * NF;
  GEMM_LOOP(56, abase, NF, bbase, NF);

  #pragma unroll
  for (int m = 0; m < 4; ++m) {
    #pragma unroll
    for (int i = 0; i < 4; ++i) {
      int rl = wm * 64 + m * 16 + (l >> 4) * 4 + i;
      int s = ss[rl];
      if (s >= 0) {
        const __half* rp = R + ((size_t)e * CAP + m0 + rl) * ND + n0 + wn * 64 + lrow;
        float* op = out + (size_t)s * ND + n0 + wn * 64 + lrow;
        #pragma unroll
        for (int n = 0; n < 4; ++n) {
          op[n * 16] = __half2float(rp[n * 16]) * acc[m][n][i];
        }
      }
    }
  }
}

extern "C" void kernel_launch(void* const* d_in, const int* in_sizes, int n_in,
                              void* d_out, int out_size, void* d_ws, size_t ws_size,
                              hipStream_t stream) {
  const float* x   = (const float*)d_in[0];
  const int*   tok = (const int*)d_in[1];
  const float* Wk  = (const float*)d_in[2];
  const float* Wr  = (const float*)d_in[3];
  const float* Wv  = (const float*)d_in[4];
  float* out = (float*)d_out;

  char* ws = (char*)d_ws;
  int*    slot_src   = (int*)ws;                        // 131072 B
  int*    rank_local = (int*)(ws + 131072);             // 131072 B
  int*    hist       = (int*)(ws + 262144);             // 16384 B
  u16*    Xd         = (u16*)(ws + (1 << 20));          // 33.5 MB
  __half* R          = (__half*)(ws + 34603008);        // 33.5 MB
  u16*    H          = (u16*)(ws + 68157440);           // 117.4 MB  (end ~177 MB)

  (void)hipMemsetAsync(d_out, 0, (size_t)out_size * sizeof(float), stream);
  (void)hipMemsetAsync(slot_src, 0xFF, NE * CAP * sizeof(int), stream);
  route1<<<64, 512, 0, stream>>>(tok, rank_local, hist);
  route2<<<64, 512, 0, stream>>>(tok, rank_local, hist, slot_src);
  dispatchx<<<NS / 4, 256, 0, stream>>>(x, slot_src, Xd);
  g1 <<<1792, 512, 0, stream>>>(Xd, Wk, H);
  g2a<<<512,  512, 0, stream>>>(Xd, Wr, R);
  g2b<<<512,  512, 0, stream>>>(H, Wv, R, slot_src, out);
}